// Round 5
// baseline (1703.594 us; speedup 1.0000x reference)
//
#include <hip/hip_runtime.h>
#include <hip/hip_bf16.h>
#include <math.h>

#define NN   10000
#define EE   160000
#define CC   128
#define RBFD 20
#define HIDD 32
#define WND  384
#define MROW 1152   // 9*128 accumulator row
#define RSTR 76     // sorted row stride (floats): 64 h | 9 y | 3 pad
#define RSTR4 19    // float4 chunks per row
#define TILE 8      // rows per gather tile (= weight-reuse group)
#define GW   8      // waves per gather block
#define WCOLS 36    // padded column stride (floats) in LDS weight bank
#define WMATF (WND * WCOLS)   // 13824 floats per matrix in LDS
#define TILEF (TILE * RSTR)   // 608 floats per tile buffer

// Static device buffers (fully rewritten each call).
__device__ __align__(16) float g_row[((size_t)EE + 2 * TILE) * RSTR]; // 48.7 MB
__device__ int   g_dst[EE + 2 * TILE];
__device__ __align__(16) float g_accu[(size_t)NN * MROW];             // 46 MB
__device__ int g_deg[NN];
__device__ int g_offs[NN + 1];
__device__ int g_rel[EE];

__device__ __forceinline__ float silu_f(float x) { return x / (1.f + __expf(-x)); }

__global__ __launch_bounds__(256) void zero_deg_kernel()
{
    int i = blockIdx.x * 256 + threadIdx.x;
    if (i < NN) g_deg[i] = 0;
}

__global__ __launch_bounds__(256) void hist_kernel(const int* __restrict__ edge_index)
{
    int e = blockIdx.x * 256 + threadIdx.x;
    if (e < EE) g_rel[e] = atomicAdd(&g_deg[edge_index[e]], 1);
}

__global__ __launch_bounds__(1024) void scan_kernel()
{
    __shared__ int s[1024];
    __shared__ int carry;
    if (threadIdx.x == 0) { carry = 0; g_offs[0] = 0; }
    __syncthreads();
    for (int base = 0; base < NN; base += 1024) {
        int i = base + threadIdx.x;
        int v = (i < NN) ? g_deg[i] : 0;
        s[threadIdx.x] = v;
        __syncthreads();
        for (int off = 1; off < 1024; off <<= 1) {
            int t = (threadIdx.x >= off) ? s[threadIdx.x - off] : 0;
            __syncthreads();
            s[threadIdx.x] += t;
            __syncthreads();
        }
        if (i < NN) g_offs[i + 1] = carry + s[threadIdx.x];
        __syncthreads();
        if (threadIdx.x == 0) carry += s[1023];
        __syncthreads();
    }
}

// Per-edge MLP1; writes combined row [64 h | 9 y | pad] to sorted position
// via per-wave LDS transpose -> coalesced 304B row stores. (unchanged)
__global__ __launch_bounds__(128) void mlp1_kernel(
    const float* __restrict__ node_feat,
    const float* __restrict__ edge_attr,
    const float* __restrict__ edge_rsh,
    const int*   __restrict__ edge_index,
    const float* __restrict__ Ws1, const float* __restrict__ bs1,
    const float* __restrict__ Wr1, const float* __restrict__ br1)
{
    __shared__ float sH[2][64][RSTR + 1];
    __shared__ int   sRow[2][64];

    int e = blockIdx.x * 128 + threadIdx.x;
    int w = threadIdx.x >> 6, l = threadIdx.x & 63;

    int s = edge_index[e];
    int t = edge_index[EE + e];
    const float* xi = node_feat + (size_t)s * CC;
    const float* xj = node_feat + (size_t)t * CC;

    float hs[HIDD];
    #pragma unroll
    for (int j = 0; j < HIDD; ++j) hs[j] = bs1[j];
    #pragma unroll 1
    for (int k4 = 0; k4 < CC / 4; ++k4) {
        float4 a = reinterpret_cast<const float4*>(xi)[k4];
        const float* wp = Ws1 + (4 * k4) * HIDD;
        #pragma unroll
        for (int j = 0; j < HIDD; ++j) {
            hs[j] = fmaf(a.x, wp[j],            hs[j]);
            hs[j] = fmaf(a.y, wp[HIDD + j],     hs[j]);
            hs[j] = fmaf(a.z, wp[2 * HIDD + j], hs[j]);
            hs[j] = fmaf(a.w, wp[3 * HIDD + j], hs[j]);
        }
    }
    #pragma unroll 1
    for (int k4 = 0; k4 < CC / 4; ++k4) {
        float4 a = reinterpret_cast<const float4*>(xj)[k4];
        const float* wp = Ws1 + (CC + 4 * k4) * HIDD;
        #pragma unroll
        for (int j = 0; j < HIDD; ++j) {
            hs[j] = fmaf(a.x, wp[j],            hs[j]);
            hs[j] = fmaf(a.y, wp[HIDD + j],     hs[j]);
            hs[j] = fmaf(a.z, wp[2 * HIDD + j], hs[j]);
            hs[j] = fmaf(a.w, wp[3 * HIDD + j], hs[j]);
        }
    }

    float hr[HIDD];
    #pragma unroll
    for (int j = 0; j < HIDD; ++j) hr[j] = br1[j];
    #pragma unroll 1
    for (int k4 = 0; k4 < RBFD / 4; ++k4) {
        float4 a = reinterpret_cast<const float4*>(edge_attr + (size_t)e * RBFD)[k4];
        const float* wp = Wr1 + (4 * k4) * HIDD;
        #pragma unroll
        for (int j = 0; j < HIDD; ++j) {
            hr[j] = fmaf(a.x, wp[j],            hr[j]);
            hr[j] = fmaf(a.y, wp[HIDD + j],     hr[j]);
            hr[j] = fmaf(a.z, wp[2 * HIDD + j], hr[j]);
            hr[j] = fmaf(a.w, wp[3 * HIDD + j], hr[j]);
        }
    }

    int row = g_offs[s] + g_rel[e];
    g_dst[row] = t;

    sRow[w][l] = row;
    #pragma unroll
    for (int j = 0; j < HIDD; ++j) {
        sH[w][l][j]        = silu_f(hs[j]);
        sH[w][l][HIDD + j] = silu_f(hr[j]);
    }
    #pragma unroll
    for (int i = 0; i < 9; ++i) sH[w][l][64 + i] = edge_rsh[(size_t)e * 9 + i];
    __syncthreads();
    #pragma unroll 4
    for (int r = 0; r < 64; ++r) {
        size_t rw = (size_t)sRow[w][r];
        g_row[rw * RSTR + l] = sH[w][r][l];
        if (l < 12) g_row[rw * RSTR + 64 + l] = sH[w][r][64 + l];
    }
}

// ---------------- gather4: wave-per-node, 8-row weight reuse ----------------

__device__ __forceinline__ float dot4(float4 a, float4 b, float c)
{
    c = fmaf(a.x, b.x, c); c = fmaf(a.y, b.y, c);
    c = fmaf(a.z, b.z, c); c = fmaf(a.w, b.w, c);
    return c;
}

__device__ __forceinline__ void tile_load(int t0, int end, int l,
    const float* __restrict__ nf, float4 (&raw)[3], float (&xj)[TILE][2])
{
    const float4* gr = reinterpret_cast<const float4*>(g_row) + (size_t)t0 * RSTR4;
    const float4 z = make_float4(0.f, 0.f, 0.f, 0.f);
    #pragma unroll
    for (int u = 0; u < 3; ++u) {
        int k = l + 64 * u;
        bool ok = (k < TILE * RSTR4) && (t0 + k / RSTR4 < end);
        raw[u] = ok ? gr[k] : z;
    }
    #pragma unroll
    for (int rr = 0; rr < TILE; ++rr) {
        int dn = (t0 + rr < end) ? g_dst[t0 + rr] : 0;
        xj[rr][0] = nf[(size_t)dn * CC + l];
        xj[rr][1] = nf[(size_t)dn * CC + 64 + l];
    }
}

__device__ __forceinline__ void tile_store_lds(float* tb, int l, const float4 (&raw)[3])
{
    float4* t4 = reinterpret_cast<float4*>(tb);
    #pragma unroll
    for (int u = 0; u < 3; ++u) {
        int k = l + 64 * u;
        if (k < TILE * RSTR4) t4[k] = raw[u];
    }
}

// One channel-half pass over an 8-row tile: weight b128s reused across all 8
// rows (peak live set ~170 VGPR; the q=0/q=1 split keeps the allocator happy).
template<int Q>
__device__ __forceinline__ void tile_pass(const float* tb,
    const float* const (&cS)[3][2], const float* const (&cR)[3][2],
    const float (&bS)[3][2], const float (&bR)[3][2],
    const float (&xj)[TILE][2], float (&acc)[9][2])
{
    float as[3][TILE], ar[3][TILE];
    #pragma unroll
    for (int m = 0; m < 3; ++m)
        #pragma unroll
        for (int r = 0; r < TILE; ++r) { as[m][r] = bS[m][Q]; ar[m][r] = bR[m][Q]; }

    #pragma unroll
    for (int j4 = 0; j4 < 8; ++j4) {
        float4 hS[TILE], hR[TILE];
        #pragma unroll
        for (int r = 0; r < TILE; ++r) {
            hS[r] = *reinterpret_cast<const float4*>(tb + r * RSTR + 4 * j4);        // broadcast
            hR[r] = *reinterpret_cast<const float4*>(tb + r * RSTR + 32 + 4 * j4);   // broadcast
        }
        #pragma unroll
        for (int m = 0; m < 3; ++m) {
            float4 wS = *reinterpret_cast<const float4*>(cS[m][Q] + 4 * j4);
            float4 wR = *reinterpret_cast<const float4*>(cR[m][Q] + 4 * j4);
            #pragma unroll
            for (int r = 0; r < TILE; ++r) {
                as[m][r] = dot4(hS[r], wS, as[m][r]);
                ar[m][r] = dot4(hR[r], wR, ar[m][r]);
            }
        }
    }

    #pragma unroll
    for (int r = 0; r < TILE; ++r) {
        const float* y = tb + r * RSTR + 64;   // zeroed for padded rows -> no-op
        float x  = xj[r][Q];
        float w0 = as[0][r] * ar[0][r] * x;
        float w1 = as[1][r] * ar[1][r] * x;
        float w2 = as[2][r] * ar[2][r] * x;
        acc[0][Q] = fmaf(w0, y[0], acc[0][Q]);
        #pragma unroll
        for (int k = 0; k < 3; ++k) acc[1 + k][Q] = fmaf(w1, y[1 + k], acc[1 + k][Q]);
        #pragma unroll
        for (int k = 0; k < 5; ++k) acc[4 + k][Q] = fmaf(w2, y[4 + k], acc[4 + k][Q]);
    }
}

__device__ __forceinline__ void tile_compute(const float* tb,
    const float* const (&cS)[3][2], const float* const (&cR)[3][2],
    const float (&bS)[3][2], const float (&bR)[3][2],
    const float (&xj)[TILE][2], float (&acc)[9][2])
{
    tile_pass<0>(tb, cS, cR, bS, bR, xj, acc);
    tile_pass<1>(tb, cS, cR, bS, bR, xj, acc);
}

__global__ __launch_bounds__(512, 2) void gather4_kernel(
    const float* __restrict__ nf,
    const float* __restrict__ Ws2, const float* __restrict__ bs2,
    const float* __restrict__ Wr2, const float* __restrict__ br2)
{
    extern __shared__ float lds[];

    // Stage Ws2/Wr2 transposed: column col at lds[mat*WMATF + col*36].
    for (int idx = threadIdx.x; idx < 2 * WND; idx += 512) {
        int mat = idx >= WND ? 1 : 0;
        int col = mat ? idx - WND : idx;
        const float* src = mat ? Wr2 : Ws2;
        float* dc = lds + mat * WMATF + col * WCOLS;
        #pragma unroll
        for (int j4 = 0; j4 < 8; ++j4) {
            float4 v = make_float4(src[(j4 * 4 + 0) * WND + col],
                                   src[(j4 * 4 + 1) * WND + col],
                                   src[(j4 * 4 + 2) * WND + col],
                                   src[(j4 * 4 + 3) * WND + col]);
            *reinterpret_cast<float4*>(dc + j4 * 4) = v;
        }
    }
    __syncthreads();

    int wv = threadIdx.x >> 6, l = threadIdx.x & 63;
    float* tb0 = lds + 2 * WMATF + wv * 2 * TILEF;
    float* tb1 = tb0 + TILEF;

    const float* cS[3][2];
    const float* cR[3][2];
    float bS[3][2], bR[3][2];
    #pragma unroll
    for (int m = 0; m < 3; ++m)
        #pragma unroll
        for (int q = 0; q < 2; ++q) {
            int col = m * CC + l + 64 * q;
            cS[m][q] = lds + col * WCOLS;
            cR[m][q] = lds + WMATF + col * WCOLS;
            bS[m][q] = bs2[col];
            bR[m][q] = br2[col];
        }

    int gw = blockIdx.x * GW + wv;
    for (int n = gw; n < NN; n += gridDim.x * GW) {
        int beg = g_offs[n], end = g_offs[n + 1];
        float acc[9][2] = {};

        float4 rawA[3], rawB[3];
        float xjA[TILE][2], xjB[TILE][2];
        tile_load(beg, end, l, nf, rawA, xjA);

        for (int t0 = beg; t0 < end; t0 += 2 * TILE) {
            tile_store_lds(tb0, l, rawA);
            tile_load(t0 + TILE, end, l, nf, rawB, xjB);          // prefetch
            tile_compute(tb0, cS, cR, bS, bR, xjA, acc);
            if (t0 + TILE < end) {
                tile_store_lds(tb1, l, rawB);
                tile_load(t0 + 2 * TILE, end, l, nf, rawA, xjA);  // prefetch
                tile_compute(tb1, cS, cR, bS, bR, xjB, acc);
            }
        }

        float* A = g_accu + (size_t)n * MROW;
        #pragma unroll
        for (int m = 0; m < 9; ++m) {
            A[m * CC + l]      = acc[m][0];
            A[m * CC + 64 + l] = acc[m][1];
        }
    }
}

// Node-wise linear, 2 nodes per block. (unchanged)
__global__ __launch_bounds__(256) void lin2_kernel(
    const float* __restrict__ W0, const float* __restrict__ b0,
    const float* __restrict__ W1, const float* __restrict__ W2,
    float* __restrict__ out)
{
    __shared__ float sA[2 * MROW];
    int n0 = blockIdx.x * 2;
    const float4* g = reinterpret_cast<const float4*>(g_accu + (size_t)n0 * MROW);
    for (int i = threadIdx.x; i < 2 * MROW / 4; i += 256)
        reinterpret_cast<float4*>(sA)[i] = g[i];
    __syncthreads();

    int d  = threadIdx.x & (CC - 1);
    int nl = threadIdx.x >> 7;
    const float* a = sA + nl * MROW;

    float acc[9];
    #pragma unroll
    for (int m = 0; m < 9; ++m) acc[m] = 0.f;

    #pragma unroll 2
    for (int cc = 0; cc < CC; ++cc) {
        float w0 = W0[cc * CC + d];
        float w1 = W1[cc * CC + d];
        float w2 = W2[cc * CC + d];
        acc[0] = fmaf(a[cc],           w0, acc[0]);
        acc[1] = fmaf(a[CC + cc],      w1, acc[1]);
        acc[2] = fmaf(a[2 * CC + cc],  w1, acc[2]);
        acc[3] = fmaf(a[3 * CC + cc],  w1, acc[3]);
        acc[4] = fmaf(a[4 * CC + cc],  w2, acc[4]);
        acc[5] = fmaf(a[5 * CC + cc],  w2, acc[5]);
        acc[6] = fmaf(a[6 * CC + cc],  w2, acc[6]);
        acc[7] = fmaf(a[7 * CC + cc],  w2, acc[7]);
        acc[8] = fmaf(a[8 * CC + cc],  w2, acc[8]);
    }

    const float inv = 0.08838834764831845f;  // 1/sqrt(128)
    size_t ob = (size_t)(n0 + nl) * MROW;
    out[ob + d] = acc[0] * inv + b0[d];
    #pragma unroll
    for (int m = 0; m < 3; ++m) out[ob + CC + d * 3 + m]     = acc[1 + m] * inv;
    #pragma unroll
    for (int m = 0; m < 5; ++m) out[ob + 4 * CC + d * 5 + m] = acc[4 + m] * inv;
}

extern "C" void kernel_launch(void* const* d_in, const int* in_sizes, int n_in,
                              void* d_out, int out_size, void* d_ws, size_t ws_size,
                              hipStream_t stream)
{
    const float* node_feat  = (const float*)d_in[0];
    const float* edge_attr  = (const float*)d_in[1];
    const float* edge_rsh   = (const float*)d_in[2];
    const int*   edge_index = (const int*)  d_in[3];
    const float* Ws1 = (const float*)d_in[4];
    const float* bs1 = (const float*)d_in[5];
    const float* Ws2 = (const float*)d_in[6];
    const float* bs2 = (const float*)d_in[7];
    const float* Wr1 = (const float*)d_in[8];
    const float* br1 = (const float*)d_in[9];
    const float* Wr2 = (const float*)d_in[10];
    const float* br2 = (const float*)d_in[11];
    const float* W0  = (const float*)d_in[12];
    const float* b0  = (const float*)d_in[13];
    const float* W1  = (const float*)d_in[14];
    const float* W2  = (const float*)d_in[15];
    float* out = (float*)d_out;

    const int ldsBytes = (2 * WMATF + GW * 2 * TILEF) * 4;   // 149504 B
    hipFuncSetAttribute(reinterpret_cast<const void*>(gather4_kernel),
                        hipFuncAttributeMaxDynamicSharedMemorySize, ldsBytes);

    zero_deg_kernel<<<(NN + 255) / 256, 256, 0, stream>>>();
    hist_kernel<<<EE / 256, 256, 0, stream>>>(edge_index);
    scan_kernel<<<1, 1024, 0, stream>>>();
    mlp1_kernel<<<EE / 128, 128, 0, stream>>>(
        node_feat, edge_attr, edge_rsh, edge_index, Ws1, bs1, Wr1, br1);
    gather4_kernel<<<256, 512, ldsBytes, stream>>>(node_feat, Ws2, bs2, Wr2, br2);
    lin2_kernel<<<NN / 2, 256, 0, stream>>>(W0, b0, W1, W2, out);
}

// Round 7
// 636.262 us; speedup vs baseline: 2.6775x; 2.6775x over previous
//
#include <hip/hip_runtime.h>
#include <hip/hip_bf16.h>
#include <math.h>

#define NN   10000
#define EE   160000
#define CC   128
#define RBFD 20
#define HIDD 32
#define WND  384
#define MROW 1152   // 9*128 accumulator row
#define RS   384    // sorted u-row stride (floats) = 1536 B, line-aligned

// Static device buffers (fully rewritten each call).
__device__ __align__(16) float g_row[(size_t)EE * RS];    // 245.8 MB: sorted u=[u0|u1|u2]
__device__ __align__(16) float g_proj[(size_t)NN * 64];   // 2.6 MB: per-node Pi(32,+bs1)|Pj(32)
__device__ __align__(16) float g_accu[(size_t)NN * MROW]; // 46 MB
__device__ int g_deg[NN];
__device__ int g_offs[NN + 1];
__device__ int g_rel[EE];
__device__ int g_ord[EE];   // sorted row -> original edge

__device__ __forceinline__ float silu_f(float x) { return x / (1.f + __expf(-x)); }

__global__ __launch_bounds__(256) void zero_deg_kernel()
{
    int i = blockIdx.x * 256 + threadIdx.x;
    if (i < NN) g_deg[i] = 0;
}

__global__ __launch_bounds__(256) void hist_kernel(const int* __restrict__ edge_index)
{
    int e = blockIdx.x * 256 + threadIdx.x;
    if (e < EE) g_rel[e] = atomicAdd(&g_deg[edge_index[e]], 1);
}

__global__ __launch_bounds__(1024) void scan_kernel()
{
    __shared__ int s[1024];
    __shared__ int carry;
    if (threadIdx.x == 0) { carry = 0; g_offs[0] = 0; }
    __syncthreads();
    for (int base = 0; base < NN; base += 1024) {
        int i = base + threadIdx.x;
        int v = (i < NN) ? g_deg[i] : 0;
        s[threadIdx.x] = v;
        __syncthreads();
        for (int off = 1; off < 1024; off <<= 1) {
            int t = (threadIdx.x >= off) ? s[threadIdx.x - off] : 0;
            __syncthreads();
            s[threadIdx.x] += t;
            __syncthreads();
        }
        if (i < NN) g_offs[i + 1] = carry + s[threadIdx.x];
        __syncthreads();
        if (threadIdx.x == 0) carry += s[1023];
        __syncthreads();
    }
}

__global__ __launch_bounds__(256) void perm_kernel(const int* __restrict__ edge_index)
{
    int e = blockIdx.x * 256 + threadIdx.x;
    if (e < EE) g_ord[g_offs[edge_index[e]] + g_rel[e]] = e;
}

// Per-node halves of MLP1: Pi = nf@Ws1[0:128]+bs1, Pj = nf@Ws1[128:256].
__global__ __launch_bounds__(64) void proj_kernel(
    const float* __restrict__ nf,
    const float* __restrict__ Ws1, const float* __restrict__ bs1)
{
    int n = blockIdx.x * 64 + threadIdx.x;
    if (n >= NN) return;
    float Pi[HIDD], Pj[HIDD];
    #pragma unroll
    for (int j = 0; j < HIDD; ++j) { Pi[j] = bs1[j]; Pj[j] = 0.f; }
    const float4* x4 = reinterpret_cast<const float4*>(nf + (size_t)n * CC);
    #pragma unroll 1
    for (int k4 = 0; k4 < CC / 4; ++k4) {
        float4 a = x4[k4];
        const float* wi = Ws1 + (4 * k4) * HIDD;
        const float* wj = Ws1 + (CC + 4 * k4) * HIDD;
        #pragma unroll
        for (int j = 0; j < HIDD; ++j) {
            Pi[j] = fmaf(a.x, wi[j], Pi[j]);
            Pi[j] = fmaf(a.y, wi[HIDD + j], Pi[j]);
            Pi[j] = fmaf(a.z, wi[2 * HIDD + j], Pi[j]);
            Pi[j] = fmaf(a.w, wi[3 * HIDD + j], Pi[j]);
            Pj[j] = fmaf(a.x, wj[j], Pj[j]);
            Pj[j] = fmaf(a.y, wj[HIDD + j], Pj[j]);
            Pj[j] = fmaf(a.z, wj[2 * HIDD + j], Pj[j]);
            Pj[j] = fmaf(a.w, wj[3 * HIDD + j], Pj[j]);
        }
    }
    float* o = g_proj + (size_t)n * 64;
    #pragma unroll
    for (int j = 0; j < HIDD; ++j) { o[j] = Pi[j]; o[HIDD + j] = Pj[j]; }
}

// Edge MLP in sorted order. Lane = sorted slot p; writes u-rows contiguously
// via conflict-free LDS transpose -> full-line 256B stores. Uniform weights
// -> scalar loads.
__global__ __launch_bounds__(64) void mlp_kernel(
    const float* __restrict__ nf,
    const float* __restrict__ edge_attr,
    const int*   __restrict__ edge_index,
    const float* __restrict__ Ws2, const float* __restrict__ bs2,
    const float* __restrict__ Wr1, const float* __restrict__ br1,
    const float* __restrict__ Wr2, const float* __restrict__ br2)
{
    __shared__ float sT[64][65];

    int p = blockIdx.x * 64 + threadIdx.x;   // grid exact: EE/64
    int l = threadIdx.x;
    int e = g_ord[p];
    int s = edge_index[e];
    int t = edge_index[EE + e];

    // ---- hs = silu(Pi[s] + Pj[t])
    float hs[HIDD];
    {
        const float4* pi = reinterpret_cast<const float4*>(g_proj + (size_t)s * 64);
        const float4* pj = reinterpret_cast<const float4*>(g_proj + (size_t)t * 64 + HIDD);
        #pragma unroll
        for (int j4 = 0; j4 < HIDD / 4; ++j4) {
            float4 a = pi[j4], b = pj[j4];
            hs[4 * j4 + 0] = silu_f(a.x + b.x);
            hs[4 * j4 + 1] = silu_f(a.y + b.y);
            hs[4 * j4 + 2] = silu_f(a.z + b.z);
            hs[4 * j4 + 3] = silu_f(a.w + b.w);
        }
    }

    // ---- hr = silu(edge_attr @ Wr1 + br1)
    float hr[HIDD];
    #pragma unroll
    for (int j = 0; j < HIDD; ++j) hr[j] = br1[j];
    #pragma unroll 1
    for (int k4 = 0; k4 < RBFD / 4; ++k4) {
        float4 a = reinterpret_cast<const float4*>(edge_attr + (size_t)e * RBFD)[k4];
        const float* wp = Wr1 + (4 * k4) * HIDD;
        #pragma unroll
        for (int j = 0; j < HIDD; ++j) {
            hr[j] = fmaf(a.x, wp[j], hr[j]);
            hr[j] = fmaf(a.y, wp[HIDD + j], hr[j]);
            hr[j] = fmaf(a.z, wp[2 * HIDD + j], hr[j]);
            hr[j] = fmaf(a.w, wp[3 * HIDD + j], hr[j]);
        }
    }
    #pragma unroll
    for (int j = 0; j < HIDD; ++j) hr[j] = silu_f(hr[j]);   // R6 bug: this was missing

    // ---- MLP2 + u = w*xj, transposed stores, 6 passes of 64 channels
    const float4* nf4 = reinterpret_cast<const float4*>(nf);
    size_t rowbase = (size_t)blockIdx.x * 64 * RS;
    #pragma unroll 1
    for (int cb = 0; cb < 2; ++cb) {
        #pragma unroll 1
        for (int m = 0; m < 3; ++m) {
            #pragma unroll 1
            for (int c4 = 0; c4 < 16; ++c4) {
                int col = m * CC + cb * 64 + c4 * 4;           // uniform
                float4 xj4 = nf4[(size_t)t * (CC / 4) + cb * 16 + c4];
                float as[4], ar[4];
                #pragma unroll
                for (int q = 0; q < 4; ++q) { as[q] = bs2[col + q]; ar[q] = br2[col + q]; }
                #pragma unroll
                for (int j = 0; j < HIDD; ++j) {
                    const float* wp = Ws2 + j * WND + col;     // uniform -> s_load
                    const float* rp = Wr2 + j * WND + col;
                    float hsv = hs[j], hrv = hr[j];
                    #pragma unroll
                    for (int q = 0; q < 4; ++q) {
                        as[q] = fmaf(hsv, wp[q], as[q]);
                        ar[q] = fmaf(hrv, rp[q], ar[q]);
                    }
                }
                float xq[4] = {xj4.x, xj4.y, xj4.z, xj4.w};
                #pragma unroll
                for (int q = 0; q < 4; ++q)
                    sT[l][c4 * 4 + q] = as[q] * ar[q] * xq[q];
            }
            __syncthreads();
            int cofs = m * CC + cb * 64;
            #pragma unroll 4
            for (int r = 0; r < 64; ++r)
                g_row[rowbase + (size_t)r * RS + cofs + l] = sT[r][l];
            __syncthreads();
        }
    }
}

// Streaming segmented sum: wave per node, lane = 2 channels.
__global__ __launch_bounds__(512) void gather_kernel(const float* __restrict__ edge_rsh)
{
    int wv = threadIdx.x >> 6, l = threadIdx.x & 63;
    int n = blockIdx.x * 8 + wv;                 // grid exact: NN/8
    int beg = g_offs[n], end = g_offs[n + 1];

    float acc[9][2] = {};
    int r = beg;
    for (; r + 1 < end; r += 2) {
        const float* R0 = g_row + (size_t)r * RS;
        const float* R1 = R0 + RS;
        int e0 = g_ord[r], e1 = g_ord[r + 1];
        const float* Y0 = edge_rsh + (size_t)e0 * 9;
        const float* Y1 = edge_rsh + (size_t)e1 * 9;
        float a0 = R0[l], a1 = R0[64 + l], a2 = R0[128 + l];
        float a3 = R0[192 + l], a4 = R0[256 + l], a5 = R0[320 + l];
        float b0 = R1[l], b1 = R1[64 + l], b2 = R1[128 + l];
        float b3 = R1[192 + l], b4 = R1[256 + l], b5 = R1[320 + l];
        #pragma unroll
        for (int k = 0; k < 9; ++k) {
            float y0 = Y0[k], y1 = Y1[k];
            float ua = (k == 0) ? a0 : (k < 4) ? a2 : a4;
            float ub = (k == 0) ? a1 : (k < 4) ? a3 : a5;
            float va = (k == 0) ? b0 : (k < 4) ? b2 : b4;
            float vb = (k == 0) ? b1 : (k < 4) ? b3 : b5;
            acc[k][0] = fmaf(ua, y0, acc[k][0]);
            acc[k][1] = fmaf(ub, y0, acc[k][1]);
            acc[k][0] = fmaf(va, y1, acc[k][0]);
            acc[k][1] = fmaf(vb, y1, acc[k][1]);
        }
    }
    if (r < end) {
        const float* R0 = g_row + (size_t)r * RS;
        int e0 = g_ord[r];
        const float* Y0 = edge_rsh + (size_t)e0 * 9;
        float a0 = R0[l], a1 = R0[64 + l], a2 = R0[128 + l];
        float a3 = R0[192 + l], a4 = R0[256 + l], a5 = R0[320 + l];
        #pragma unroll
        for (int k = 0; k < 9; ++k) {
            float y0 = Y0[k];
            float ua = (k == 0) ? a0 : (k < 4) ? a2 : a4;
            float ub = (k == 0) ? a1 : (k < 4) ? a3 : a5;
            acc[k][0] = fmaf(ua, y0, acc[k][0]);
            acc[k][1] = fmaf(ub, y0, acc[k][1]);
        }
    }

    float* A = g_accu + (size_t)n * MROW;
    #pragma unroll
    for (int m = 0; m < 9; ++m) {
        A[m * CC + l]      = acc[m][0];
        A[m * CC + 64 + l] = acc[m][1];
    }
}

// Node-wise linear, 2 nodes per block. (unchanged)
__global__ __launch_bounds__(256) void lin2_kernel(
    const float* __restrict__ W0, const float* __restrict__ b0,
    const float* __restrict__ W1, const float* __restrict__ W2,
    float* __restrict__ out)
{
    __shared__ float sA[2 * MROW];
    int n0 = blockIdx.x * 2;
    const float4* g = reinterpret_cast<const float4*>(g_accu + (size_t)n0 * MROW);
    for (int i = threadIdx.x; i < 2 * MROW / 4; i += 256)
        reinterpret_cast<float4*>(sA)[i] = g[i];
    __syncthreads();

    int d  = threadIdx.x & (CC - 1);
    int nl = threadIdx.x >> 7;
    const float* a = sA + nl * MROW;

    float acc[9];
    #pragma unroll
    for (int m = 0; m < 9; ++m) acc[m] = 0.f;

    #pragma unroll 2
    for (int cc = 0; cc < CC; ++cc) {
        float w0 = W0[cc * CC + d];
        float w1 = W1[cc * CC + d];
        float w2 = W2[cc * CC + d];
        acc[0] = fmaf(a[cc],           w0, acc[0]);
        acc[1] = fmaf(a[CC + cc],      w1, acc[1]);
        acc[2] = fmaf(a[2 * CC + cc],  w1, acc[2]);
        acc[3] = fmaf(a[3 * CC + cc],  w1, acc[3]);
        acc[4] = fmaf(a[4 * CC + cc],  w2, acc[4]);
        acc[5] = fmaf(a[5 * CC + cc],  w2, acc[5]);
        acc[6] = fmaf(a[6 * CC + cc],  w2, acc[6]);
        acc[7] = fmaf(a[7 * CC + cc],  w2, acc[7]);
        acc[8] = fmaf(a[8 * CC + cc],  w2, acc[8]);
    }

    const float inv = 0.08838834764831845f;  // 1/sqrt(128)
    size_t ob = (size_t)(n0 + nl) * MROW;
    out[ob + d] = acc[0] * inv + b0[d];
    #pragma unroll
    for (int m = 0; m < 3; ++m) out[ob + CC + d * 3 + m]     = acc[1 + m] * inv;
    #pragma unroll
    for (int m = 0; m < 5; ++m) out[ob + 4 * CC + d * 5 + m] = acc[4 + m] * inv;
}

extern "C" void kernel_launch(void* const* d_in, const int* in_sizes, int n_in,
                              void* d_out, int out_size, void* d_ws, size_t ws_size,
                              hipStream_t stream)
{
    const float* node_feat  = (const float*)d_in[0];
    const float* edge_attr  = (const float*)d_in[1];
    const float* edge_rsh   = (const float*)d_in[2];
    const int*   edge_index = (const int*)  d_in[3];
    const float* Ws1 = (const float*)d_in[4];
    const float* bs1 = (const float*)d_in[5];
    const float* Ws2 = (const float*)d_in[6];
    const float* bs2 = (const float*)d_in[7];
    const float* Wr1 = (const float*)d_in[8];
    const float* br1 = (const float*)d_in[9];
    const float* Wr2 = (const float*)d_in[10];
    const float* br2 = (const float*)d_in[11];
    const float* W0  = (const float*)d_in[12];
    const float* b0  = (const float*)d_in[13];
    const float* W1  = (const float*)d_in[14];
    const float* W2  = (const float*)d_in[15];
    float* out = (float*)d_out;

    zero_deg_kernel<<<(NN + 255) / 256, 256, 0, stream>>>();
    hist_kernel<<<EE / 256, 256, 0, stream>>>(edge_index);
    scan_kernel<<<1, 1024, 0, stream>>>();
    perm_kernel<<<EE / 256, 256, 0, stream>>>(edge_index);
    proj_kernel<<<(NN + 63) / 64, 64, 0, stream>>>(node_feat, Ws1, bs1);
    mlp_kernel<<<EE / 64, 64, 0, stream>>>(
        node_feat, edge_attr, edge_index, Ws2, bs2, Wr1, br1, Wr2, br2);
    gather_kernel<<<NN / 8, 512, 0, stream>>>(edge_rsh);
    lin2_kernel<<<NN / 2, 256, 0, stream>>>(W0, b0, W1, W2, out);
}

// Round 8
// 559.001 us; speedup vs baseline: 3.0476x; 1.1382x over previous
//
#include <hip/hip_runtime.h>
#include <hip/hip_bf16.h>
#include <math.h>

#define NN   10000
#define EE   160000
#define CC   128
#define RBFD 20
#define HIDD 32
#define WND  384
#define MROW 1152   // 9*128 accumulator row
#define RS   384    // sorted u-row stride (floats) = 1536 B, line-aligned

// Static device buffers (fully rewritten each call).
__device__ __align__(16) float g_row[(size_t)EE * RS];    // 245.8 MB: sorted u=[u0|u1|u2]
__device__ __align__(16) float g_proj[(size_t)NN * 64];   // 2.6 MB: per-node Pi(32,+bs1)|Pj(32)
__device__ __align__(16) float g_accu[(size_t)NN * MROW]; // 46 MB
__device__ int g_deg[NN];
__device__ int g_offs[NN + 1];
__device__ int g_rel[EE];
__device__ int g_ord[EE];   // sorted row -> original edge

__device__ __forceinline__ float silu_f(float x) { return x / (1.f + __expf(-x)); }

__global__ __launch_bounds__(256) void zero_deg_kernel()
{
    int i = blockIdx.x * 256 + threadIdx.x;
    if (i < NN) g_deg[i] = 0;
}

__global__ __launch_bounds__(256) void hist_kernel(const int* __restrict__ edge_index)
{
    int e = blockIdx.x * 256 + threadIdx.x;
    if (e < EE) g_rel[e] = atomicAdd(&g_deg[edge_index[e]], 1);
}

__global__ __launch_bounds__(1024) void scan_kernel()
{
    __shared__ int s[1024];
    __shared__ int carry;
    if (threadIdx.x == 0) { carry = 0; g_offs[0] = 0; }
    __syncthreads();
    for (int base = 0; base < NN; base += 1024) {
        int i = base + threadIdx.x;
        int v = (i < NN) ? g_deg[i] : 0;
        s[threadIdx.x] = v;
        __syncthreads();
        for (int off = 1; off < 1024; off <<= 1) {
            int t = (threadIdx.x >= off) ? s[threadIdx.x - off] : 0;
            __syncthreads();
            s[threadIdx.x] += t;
            __syncthreads();
        }
        if (i < NN) g_offs[i + 1] = carry + s[threadIdx.x];
        __syncthreads();
        if (threadIdx.x == 0) carry += s[1023];
        __syncthreads();
    }
}

__global__ __launch_bounds__(256) void perm_kernel(const int* __restrict__ edge_index)
{
    int e = blockIdx.x * 256 + threadIdx.x;
    if (e < EE) g_ord[g_offs[edge_index[e]] + g_rel[e]] = e;
}

// Per-node halves of MLP1: Pi = nf@Ws1[0:128]+bs1, Pj = nf@Ws1[128:256].
__global__ __launch_bounds__(64) void proj_kernel(
    const float* __restrict__ nf,
    const float* __restrict__ Ws1, const float* __restrict__ bs1)
{
    int n = blockIdx.x * 64 + threadIdx.x;
    if (n >= NN) return;
    float Pi[HIDD], Pj[HIDD];
    #pragma unroll
    for (int j = 0; j < HIDD; ++j) { Pi[j] = bs1[j]; Pj[j] = 0.f; }
    const float4* x4 = reinterpret_cast<const float4*>(nf + (size_t)n * CC);
    #pragma unroll 1
    for (int k4 = 0; k4 < CC / 4; ++k4) {
        float4 a = x4[k4];
        const float* wi = Ws1 + (4 * k4) * HIDD;
        const float* wj = Ws1 + (CC + 4 * k4) * HIDD;
        #pragma unroll
        for (int j = 0; j < HIDD; ++j) {
            Pi[j] = fmaf(a.x, wi[j], Pi[j]);
            Pi[j] = fmaf(a.y, wi[HIDD + j], Pi[j]);
            Pi[j] = fmaf(a.z, wi[2 * HIDD + j], Pi[j]);
            Pi[j] = fmaf(a.w, wi[3 * HIDD + j], Pi[j]);
            Pj[j] = fmaf(a.x, wj[j], Pj[j]);
            Pj[j] = fmaf(a.y, wj[HIDD + j], Pj[j]);
            Pj[j] = fmaf(a.z, wj[2 * HIDD + j], Pj[j]);
            Pj[j] = fmaf(a.w, wj[3 * HIDD + j], Pj[j]);
        }
    }
    float* o = g_proj + (size_t)n * 64;
    #pragma unroll
    for (int j = 0; j < HIDD; ++j) { o[j] = Pi[j]; o[HIDD + j] = Pj[j]; }
}

// Edge MLP in sorted order. 128-thr blocks = 2 waves, per-wave 16-channel
// transpose tile (8.7 KB LDS total) -> ~16 waves/CU for latency hiding.
// Uniform weights -> scalar loads; coalesced full-line row stores.
__global__ __launch_bounds__(128) void mlp_kernel(
    const float* __restrict__ nf,
    const float* __restrict__ edge_attr,
    const int*   __restrict__ edge_index,
    const float* __restrict__ Ws2, const float* __restrict__ bs2,
    const float* __restrict__ Wr1, const float* __restrict__ br1,
    const float* __restrict__ Wr2, const float* __restrict__ br2)
{
    __shared__ float sT[2][64][17];

    int w = threadIdx.x >> 6, l = threadIdx.x & 63;
    int p = blockIdx.x * 128 + threadIdx.x;   // grid exact: EE/128
    int e = g_ord[p];
    int s = edge_index[e];
    int t = edge_index[EE + e];

    // ---- hs = silu(Pi[s] + Pj[t])
    float hs[HIDD];
    {
        const float4* pi = reinterpret_cast<const float4*>(g_proj + (size_t)s * 64);
        const float4* pj = reinterpret_cast<const float4*>(g_proj + (size_t)t * 64 + HIDD);
        #pragma unroll
        for (int j4 = 0; j4 < HIDD / 4; ++j4) {
            float4 a = pi[j4], b = pj[j4];
            hs[4 * j4 + 0] = silu_f(a.x + b.x);
            hs[4 * j4 + 1] = silu_f(a.y + b.y);
            hs[4 * j4 + 2] = silu_f(a.z + b.z);
            hs[4 * j4 + 3] = silu_f(a.w + b.w);
        }
    }

    // ---- hr = silu(edge_attr @ Wr1 + br1)
    float hr[HIDD];
    #pragma unroll
    for (int j = 0; j < HIDD; ++j) hr[j] = br1[j];
    #pragma unroll 1
    for (int k4 = 0; k4 < RBFD / 4; ++k4) {
        float4 a = reinterpret_cast<const float4*>(edge_attr + (size_t)e * RBFD)[k4];
        const float* wp = Wr1 + (4 * k4) * HIDD;
        #pragma unroll
        for (int j = 0; j < HIDD; ++j) {
            hr[j] = fmaf(a.x, wp[j], hr[j]);
            hr[j] = fmaf(a.y, wp[HIDD + j], hr[j]);
            hr[j] = fmaf(a.z, wp[2 * HIDD + j], hr[j]);
            hr[j] = fmaf(a.w, wp[3 * HIDD + j], hr[j]);
        }
    }
    #pragma unroll
    for (int j = 0; j < HIDD; ++j) hr[j] = silu_f(hr[j]);

    // ---- MLP2 + u = w*xj; 24 phases of 16 channels; per-wave LDS transpose
    const float4* nf4 = reinterpret_cast<const float4*>(nf);
    size_t rowbase = (size_t)(blockIdx.x * 128 + w * 64) * RS;

    #pragma unroll 1
    for (int cg = 0; cg < 8; ++cg) {
        // xj channels for this group, reused across the 3 m-phases
        float4 xj4[4];
        #pragma unroll
        for (int k = 0; k < 4; ++k)
            xj4[k] = nf4[(size_t)t * (CC / 4) + cg * 4 + k];

        #pragma unroll 1
        for (int m = 0; m < 3; ++m) {
            int col0 = m * CC + cg * 16;   // uniform
            #pragma unroll 1
            for (int c4 = 0; c4 < 4; ++c4) {
                int col = col0 + c4 * 4;
                float as[4], ar[4];
                #pragma unroll
                for (int q = 0; q < 4; ++q) { as[q] = bs2[col + q]; ar[q] = br2[col + q]; }
                #pragma unroll
                for (int j = 0; j < HIDD; ++j) {
                    const float* wp = Ws2 + j * WND + col;   // uniform -> s_load
                    const float* rp = Wr2 + j * WND + col;
                    float hsv = hs[j], hrv = hr[j];
                    #pragma unroll
                    for (int q = 0; q < 4; ++q) {
                        as[q] = fmaf(hsv, wp[q], as[q]);
                        ar[q] = fmaf(hrv, rp[q], ar[q]);
                    }
                }
                float xq[4] = {xj4[c4].x, xj4[c4].y, xj4[c4].z, xj4[c4].w};
                #pragma unroll
                for (int q = 0; q < 4; ++q)
                    sT[w][l][c4 * 4 + q] = as[q] * ar[q] * xq[q];
            }
            __syncthreads();
            // dump: 4 rows x 16 channels per iteration, 64B contiguous per row
            int rg = l >> 4, c = l & 15;
            #pragma unroll 4
            for (int it = 0; it < 16; ++it) {
                int r = it * 4 + rg;
                g_row[rowbase + (size_t)r * RS + col0 + c] = sT[w][r][c];
            }
            __syncthreads();
        }
    }
}

// Streaming segmented sum: wave per node, lane = 2 channels.
__global__ __launch_bounds__(512) void gather_kernel(const float* __restrict__ edge_rsh)
{
    int wv = threadIdx.x >> 6, l = threadIdx.x & 63;
    int n = blockIdx.x * 8 + wv;                 // grid exact: NN/8
    int beg = g_offs[n], end = g_offs[n + 1];

    float acc[9][2] = {};
    int r = beg;
    for (; r + 1 < end; r += 2) {
        const float* R0 = g_row + (size_t)r * RS;
        const float* R1 = R0 + RS;
        int e0 = g_ord[r], e1 = g_ord[r + 1];
        const float* Y0 = edge_rsh + (size_t)e0 * 9;
        const float* Y1 = edge_rsh + (size_t)e1 * 9;
        float a0 = R0[l], a1 = R0[64 + l], a2 = R0[128 + l];
        float a3 = R0[192 + l], a4 = R0[256 + l], a5 = R0[320 + l];
        float b0 = R1[l], b1 = R1[64 + l], b2 = R1[128 + l];
        float b3 = R1[192 + l], b4 = R1[256 + l], b5 = R1[320 + l];
        #pragma unroll
        for (int k = 0; k < 9; ++k) {
            float y0 = Y0[k], y1 = Y1[k];
            float ua = (k == 0) ? a0 : (k < 4) ? a2 : a4;
            float ub = (k == 0) ? a1 : (k < 4) ? a3 : a5;
            float va = (k == 0) ? b0 : (k < 4) ? b2 : b4;
            float vb = (k == 0) ? b1 : (k < 4) ? b3 : b5;
            acc[k][0] = fmaf(ua, y0, acc[k][0]);
            acc[k][1] = fmaf(ub, y0, acc[k][1]);
            acc[k][0] = fmaf(va, y1, acc[k][0]);
            acc[k][1] = fmaf(vb, y1, acc[k][1]);
        }
    }
    if (r < end) {
        const float* R0 = g_row + (size_t)r * RS;
        int e0 = g_ord[r];
        const float* Y0 = edge_rsh + (size_t)e0 * 9;
        float a0 = R0[l], a1 = R0[64 + l], a2 = R0[128 + l];
        float a3 = R0[192 + l], a4 = R0[256 + l], a5 = R0[320 + l];
        #pragma unroll
        for (int k = 0; k < 9; ++k) {
            float y0 = Y0[k];
            float ua = (k == 0) ? a0 : (k < 4) ? a2 : a4;
            float ub = (k == 0) ? a1 : (k < 4) ? a3 : a5;
            acc[k][0] = fmaf(ua, y0, acc[k][0]);
            acc[k][1] = fmaf(ub, y0, acc[k][1]);
        }
    }

    float* A = g_accu + (size_t)n * MROW;
    #pragma unroll
    for (int m = 0; m < 9; ++m) {
        A[m * CC + l]      = acc[m][0];
        A[m * CC + 64 + l] = acc[m][1];
    }
}

// Node-wise linear, 2 nodes per block. (unchanged)
__global__ __launch_bounds__(256) void lin2_kernel(
    const float* __restrict__ W0, const float* __restrict__ b0,
    const float* __restrict__ W1, const float* __restrict__ W2,
    float* __restrict__ out)
{
    __shared__ float sA[2 * MROW];
    int n0 = blockIdx.x * 2;
    const float4* g = reinterpret_cast<const float4*>(g_accu + (size_t)n0 * MROW);
    for (int i = threadIdx.x; i < 2 * MROW / 4; i += 256)
        reinterpret_cast<float4*>(sA)[i] = g[i];
    __syncthreads();

    int d  = threadIdx.x & (CC - 1);
    int nl = threadIdx.x >> 7;
    const float* a = sA + nl * MROW;

    float acc[9];
    #pragma unroll
    for (int m = 0; m < 9; ++m) acc[m] = 0.f;

    #pragma unroll 2
    for (int cc = 0; cc < CC; ++cc) {
        float w0 = W0[cc * CC + d];
        float w1 = W1[cc * CC + d];
        float w2 = W2[cc * CC + d];
        acc[0] = fmaf(a[cc],           w0, acc[0]);
        acc[1] = fmaf(a[CC + cc],      w1, acc[1]);
        acc[2] = fmaf(a[2 * CC + cc],  w1, acc[2]);
        acc[3] = fmaf(a[3 * CC + cc],  w1, acc[3]);
        acc[4] = fmaf(a[4 * CC + cc],  w2, acc[4]);
        acc[5] = fmaf(a[5 * CC + cc],  w2, acc[5]);
        acc[6] = fmaf(a[6 * CC + cc],  w2, acc[6]);
        acc[7] = fmaf(a[7 * CC + cc],  w2, acc[7]);
        acc[8] = fmaf(a[8 * CC + cc],  w2, acc[8]);
    }

    const float inv = 0.08838834764831845f;  // 1/sqrt(128)
    size_t ob = (size_t)(n0 + nl) * MROW;
    out[ob + d] = acc[0] * inv + b0[d];
    #pragma unroll
    for (int m = 0; m < 3; ++m) out[ob + CC + d * 3 + m]     = acc[1 + m] * inv;
    #pragma unroll
    for (int m = 0; m < 5; ++m) out[ob + 4 * CC + d * 5 + m] = acc[4 + m] * inv;
}

extern "C" void kernel_launch(void* const* d_in, const int* in_sizes, int n_in,
                              void* d_out, int out_size, void* d_ws, size_t ws_size,
                              hipStream_t stream)
{
    const float* node_feat  = (const float*)d_in[0];
    const float* edge_attr  = (const float*)d_in[1];
    const float* edge_rsh   = (const float*)d_in[2];
    const int*   edge_index = (const int*)  d_in[3];
    const float* Ws1 = (const float*)d_in[4];
    const float* bs1 = (const float*)d_in[5];
    const float* Ws2 = (const float*)d_in[6];
    const float* bs2 = (const float*)d_in[7];
    const float* Wr1 = (const float*)d_in[8];
    const float* br1 = (const float*)d_in[9];
    const float* Wr2 = (const float*)d_in[10];
    const float* br2 = (const float*)d_in[11];
    const float* W0  = (const float*)d_in[12];
    const float* b0  = (const float*)d_in[13];
    const float* W1  = (const float*)d_in[14];
    const float* W2  = (const float*)d_in[15];
    float* out = (float*)d_out;

    zero_deg_kernel<<<(NN + 255) / 256, 256, 0, stream>>>();
    hist_kernel<<<EE / 256, 256, 0, stream>>>(edge_index);
    scan_kernel<<<1, 1024, 0, stream>>>();
    perm_kernel<<<EE / 256, 256, 0, stream>>>(edge_index);
    proj_kernel<<<(NN + 63) / 64, 64, 0, stream>>>(node_feat, Ws1, bs1);
    mlp_kernel<<<EE / 128, 128, 0, stream>>>(
        node_feat, edge_attr, edge_index, Ws2, bs2, Wr1, br1, Wr2, br2);
    gather_kernel<<<NN / 8, 512, 0, stream>>>(edge_rsh);
    lin2_kernel<<<NN / 2, 256, 0, stream>>>(W0, b0, W1, W2, out);
}

// Round 9
// 465.380 us; speedup vs baseline: 3.6607x; 1.2012x over previous
//
#include <hip/hip_runtime.h>
#include <hip/hip_bf16.h>
#include <math.h>

#define NN   10000
#define EE   160000
#define CC   128
#define RBFD 20
#define HIDD 32
#define WND  384
#define MROW 1152   // 9*128 accumulator row
#define RS   384    // sorted u-row stride (floats) = 1536 B, line-aligned

// Static device buffers (fully rewritten each call).
__device__ __align__(16) float g_row[(size_t)EE * RS];    // 245.8 MB: sorted u=[u0|u1|u2]
__device__ __align__(16) float g_proj[(size_t)NN * 64];   // 2.6 MB: per-node Pi(32,+bs1)|Pj(32)
__device__ __align__(16) float g_accu[(size_t)NN * MROW]; // 46 MB
__device__ int g_deg[NN];
__device__ int g_offs[NN + 1];
__device__ int g_rel[EE];
__device__ int g_ord[EE];   // sorted row -> original edge

__device__ __forceinline__ float silu_f(float x) { return x / (1.f + __expf(-x)); }

__global__ __launch_bounds__(256) void zero_deg_kernel()
{
    int i = blockIdx.x * 256 + threadIdx.x;
    if (i < NN) g_deg[i] = 0;
}

__global__ __launch_bounds__(256) void hist_kernel(const int* __restrict__ edge_index)
{
    int e = blockIdx.x * 256 + threadIdx.x;
    if (e < EE) g_rel[e] = atomicAdd(&g_deg[edge_index[e]], 1);
}

// Blocked scan: 256 threads x 40 items, one block.
__global__ __launch_bounds__(256) void scan_kernel()
{
    __shared__ int sP[256];
    int t = threadIdx.x;
    int lo = t * 40, hi = min(lo + 40, NN);
    int sum = 0;
    for (int i = lo; i < hi; ++i) sum += g_deg[i];
    sP[t] = sum;
    __syncthreads();
    for (int off = 1; off < 256; off <<= 1) {
        int v = (t >= off) ? sP[t - off] : 0;
        __syncthreads();
        sP[t] += v;
        __syncthreads();
    }
    int run = sP[t] - sum;   // exclusive prefix
    if (t == 0) g_offs[0] = 0;
    for (int i = lo; i < hi; ++i) { run += g_deg[i]; g_offs[i + 1] = run; }
}

__global__ __launch_bounds__(256) void perm_kernel(const int* __restrict__ edge_index)
{
    int e = blockIdx.x * 256 + threadIdx.x;
    if (e < EE) g_ord[g_offs[edge_index[e]] + g_rel[e]] = e;
}

// Per-node halves of MLP1: Pi = nf@Ws1[0:128]+bs1, Pj = nf@Ws1[128:256].
__global__ __launch_bounds__(64) void proj_kernel(
    const float* __restrict__ nf,
    const float* __restrict__ Ws1, const float* __restrict__ bs1)
{
    int n = blockIdx.x * 64 + threadIdx.x;
    if (n >= NN) return;
    float Pi[HIDD], Pj[HIDD];
    #pragma unroll
    for (int j = 0; j < HIDD; ++j) { Pi[j] = bs1[j]; Pj[j] = 0.f; }
    const float4* x4 = reinterpret_cast<const float4*>(nf + (size_t)n * CC);
    #pragma unroll 1
    for (int k4 = 0; k4 < CC / 4; ++k4) {
        float4 a = x4[k4];
        const float* wi = Ws1 + (4 * k4) * HIDD;
        const float* wj = Ws1 + (CC + 4 * k4) * HIDD;
        #pragma unroll
        for (int j = 0; j < HIDD; ++j) {
            Pi[j] = fmaf(a.x, wi[j], Pi[j]);
            Pi[j] = fmaf(a.y, wi[HIDD + j], Pi[j]);
            Pi[j] = fmaf(a.z, wi[2 * HIDD + j], Pi[j]);
            Pi[j] = fmaf(a.w, wi[3 * HIDD + j], Pi[j]);
            Pj[j] = fmaf(a.x, wj[j], Pj[j]);
            Pj[j] = fmaf(a.y, wj[HIDD + j], Pj[j]);
            Pj[j] = fmaf(a.z, wj[2 * HIDD + j], Pj[j]);
            Pj[j] = fmaf(a.w, wj[3 * HIDD + j], Pj[j]);
        }
    }
    float* o = g_proj + (size_t)n * 64;
    #pragma unroll
    for (int j = 0; j < HIDD; ++j) { o[j] = Pi[j]; o[HIDD + j] = Pj[j]; }
}

// Edge MLP, sorted order, lane=edge. Weight sub-chunks staged in LDS and read
// as broadcast ds_read_b128 (VGPR dests -> deep pipelining, unlike s_loads).
// 32-channel per-wave transpose tile -> 128B full-line row stores, no RFO.
__global__ __launch_bounds__(128) void mlp_kernel(
    const float* __restrict__ nf,
    const float* __restrict__ edge_attr,
    const int*   __restrict__ edge_index,
    const float* __restrict__ Ws2, const float* __restrict__ bs2,
    const float* __restrict__ Wr1, const float* __restrict__ br1,
    const float* __restrict__ Wr2, const float* __restrict__ br2)
{
    __shared__ float sW[2][32][36];   // 9.2 KB: current 32-col weight sub-chunk
    __shared__ float sBias[2][32];    // 256 B
    __shared__ float sT[2][64][33];   // 16.9 KB: per-wave 64-edge x 32-col tile

    int w = threadIdx.x >> 6, l = threadIdx.x & 63;
    int p = blockIdx.x * 128 + threadIdx.x;   // grid exact: EE/128
    int e = g_ord[p];
    int s = edge_index[e];
    int t = edge_index[EE + e];

    // ---- hs = silu(Pi[s] + Pj[t])
    float hs[HIDD];
    {
        const float4* pi = reinterpret_cast<const float4*>(g_proj + (size_t)s * 64);
        const float4* pj = reinterpret_cast<const float4*>(g_proj + (size_t)t * 64 + HIDD);
        #pragma unroll
        for (int j4 = 0; j4 < HIDD / 4; ++j4) {
            float4 a = pi[j4], b = pj[j4];
            hs[4 * j4 + 0] = silu_f(a.x + b.x);
            hs[4 * j4 + 1] = silu_f(a.y + b.y);
            hs[4 * j4 + 2] = silu_f(a.z + b.z);
            hs[4 * j4 + 3] = silu_f(a.w + b.w);
        }
    }

    // ---- hr = silu(edge_attr @ Wr1 + br1)
    float hr[HIDD];
    #pragma unroll
    for (int j = 0; j < HIDD; ++j) hr[j] = br1[j];
    #pragma unroll 1
    for (int k4 = 0; k4 < RBFD / 4; ++k4) {
        float4 a = reinterpret_cast<const float4*>(edge_attr + (size_t)e * RBFD)[k4];
        const float* wp = Wr1 + (4 * k4) * HIDD;
        #pragma unroll
        for (int j = 0; j < HIDD; ++j) {
            hr[j] = fmaf(a.x, wp[j], hr[j]);
            hr[j] = fmaf(a.y, wp[HIDD + j], hr[j]);
            hr[j] = fmaf(a.z, wp[2 * HIDD + j], hr[j]);
            hr[j] = fmaf(a.w, wp[3 * HIDD + j], hr[j]);
        }
    }
    #pragma unroll
    for (int j = 0; j < HIDD; ++j) hr[j] = silu_f(hr[j]);

    const float4* nf4 = reinterpret_cast<const float4*>(nf);
    size_t rowbase = (size_t)(blockIdx.x * 128 + w * 64) * RS;

    // ---- 12 sub-chunks of 32 cols: stage weights -> compute -> full-line dump
    #pragma unroll 1
    for (int ch = 0; ch < 12; ++ch) {
        int c0 = ch * 32;                 // global weight col base (0..383)
        __syncthreads();                  // prior sub-chunk's sW reads done
        {
            // stage 2*32*32 floats: 128 thr x 16 floats (4x float4)
            int mat = threadIdx.x >> 6;          // 0..1
            int j   = (threadIdx.x >> 1) & 31;   // 0..31
            int q   = threadIdx.x & 1;           // 0..1
            const float4* src = reinterpret_cast<const float4*>(
                (mat ? Wr2 : Ws2) + (size_t)j * WND + c0 + q * 16);
            float4* dst = reinterpret_cast<float4*>(&sW[mat][j][q * 16]);
            dst[0] = src[0]; dst[1] = src[1]; dst[2] = src[2]; dst[3] = src[3];
            if (threadIdx.x < 64) {
                int mt = threadIdx.x >> 5, c = threadIdx.x & 31;
                sBias[mt][c] = (mt ? br2 : bs2)[c0 + c];
            }
        }
        __syncthreads();

        // compute 8 x 4 cols into per-wave transpose tile
        #pragma unroll 1
        for (int c4 = 0; c4 < 8; ++c4) {
            int colL = c4 * 4;
            float4 xjv = nf4[(size_t)t * (CC / 4) + ((c0 & 127) >> 2) + c4];
            float4 b0 = *reinterpret_cast<const float4*>(&sBias[0][colL]);
            float4 b1 = *reinterpret_cast<const float4*>(&sBias[1][colL]);
            float as[4] = {b0.x, b0.y, b0.z, b0.w};
            float ar[4] = {b1.x, b1.y, b1.z, b1.w};
            #pragma unroll
            for (int jg = 0; jg < 8; ++jg) {
                float4 wv[4], rv[4];
                #pragma unroll
                for (int k = 0; k < 4; ++k) {
                    wv[k] = *reinterpret_cast<const float4*>(&sW[0][jg * 4 + k][colL]);
                    rv[k] = *reinterpret_cast<const float4*>(&sW[1][jg * 4 + k][colL]);
                }
                #pragma unroll
                for (int k = 0; k < 4; ++k) {
                    float hsv = hs[jg * 4 + k], hrv = hr[jg * 4 + k];
                    as[0] = fmaf(hsv, wv[k].x, as[0]); as[1] = fmaf(hsv, wv[k].y, as[1]);
                    as[2] = fmaf(hsv, wv[k].z, as[2]); as[3] = fmaf(hsv, wv[k].w, as[3]);
                    ar[0] = fmaf(hrv, rv[k].x, ar[0]); ar[1] = fmaf(hrv, rv[k].y, ar[1]);
                    ar[2] = fmaf(hrv, rv[k].z, ar[2]); ar[3] = fmaf(hrv, rv[k].w, ar[3]);
                }
            }
            float xq[4] = {xjv.x, xjv.y, xjv.z, xjv.w};
            #pragma unroll
            for (int q = 0; q < 4; ++q)
                sT[w][l][colL + q] = as[q] * ar[q] * xq[q];
        }

        // per-wave dump: 2 rows x 32 cols (= 2 full 128B lines) per iteration.
        // No block barrier: sT slice is wave-private; DS ops are in-order.
        int rg = l >> 5, c = l & 31;
        #pragma unroll 4
        for (int it = 0; it < 32; ++it) {
            int r = it * 2 + rg;
            g_row[rowbase + (size_t)r * RS + c0 + c] = sT[w][r][c];
        }
    }
}

// Streaming segmented sum: wave per node, lane = 2 channels.
__global__ __launch_bounds__(512) void gather_kernel(const float* __restrict__ edge_rsh)
{
    int wv = threadIdx.x >> 6, l = threadIdx.x & 63;
    int n = blockIdx.x * 8 + wv;                 // grid exact: NN/8
    int beg = g_offs[n], end = g_offs[n + 1];

    float acc[9][2] = {};
    int r = beg;
    for (; r + 1 < end; r += 2) {
        const float* R0 = g_row + (size_t)r * RS;
        const float* R1 = R0 + RS;
        int e0 = g_ord[r], e1 = g_ord[r + 1];
        const float* Y0 = edge_rsh + (size_t)e0 * 9;
        const float* Y1 = edge_rsh + (size_t)e1 * 9;
        float a0 = R0[l], a1 = R0[64 + l], a2 = R0[128 + l];
        float a3 = R0[192 + l], a4 = R0[256 + l], a5 = R0[320 + l];
        float b0 = R1[l], b1 = R1[64 + l], b2 = R1[128 + l];
        float b3 = R1[192 + l], b4 = R1[256 + l], b5 = R1[320 + l];
        #pragma unroll
        for (int k = 0; k < 9; ++k) {
            float y0 = Y0[k], y1 = Y1[k];
            float ua = (k == 0) ? a0 : (k < 4) ? a2 : a4;
            float ub = (k == 0) ? a1 : (k < 4) ? a3 : a5;
            float va = (k == 0) ? b0 : (k < 4) ? b2 : b4;
            float vb = (k == 0) ? b1 : (k < 4) ? b3 : b5;
            acc[k][0] = fmaf(ua, y0, acc[k][0]);
            acc[k][1] = fmaf(ub, y0, acc[k][1]);
            acc[k][0] = fmaf(va, y1, acc[k][0]);
            acc[k][1] = fmaf(vb, y1, acc[k][1]);
        }
    }
    if (r < end) {
        const float* R0 = g_row + (size_t)r * RS;
        int e0 = g_ord[r];
        const float* Y0 = edge_rsh + (size_t)e0 * 9;
        float a0 = R0[l], a1 = R0[64 + l], a2 = R0[128 + l];
        float a3 = R0[192 + l], a4 = R0[256 + l], a5 = R0[320 + l];
        #pragma unroll
        for (int k = 0; k < 9; ++k) {
            float y0 = Y0[k];
            float ua = (k == 0) ? a0 : (k < 4) ? a2 : a4;
            float ub = (k == 0) ? a1 : (k < 4) ? a3 : a5;
            acc[k][0] = fmaf(ua, y0, acc[k][0]);
            acc[k][1] = fmaf(ub, y0, acc[k][1]);
        }
    }

    float* A = g_accu + (size_t)n * MROW;
    #pragma unroll
    for (int m = 0; m < 9; ++m) {
        A[m * CC + l]      = acc[m][0];
        A[m * CC + 64 + l] = acc[m][1];
    }
}

// Node-wise linear, 2 nodes per block. (unchanged)
__global__ __launch_bounds__(256) void lin2_kernel(
    const float* __restrict__ W0, const float* __restrict__ b0,
    const float* __restrict__ W1, const float* __restrict__ W2,
    float* __restrict__ out)
{
    __shared__ float sA[2 * MROW];
    int n0 = blockIdx.x * 2;
    const float4* g = reinterpret_cast<const float4*>(g_accu + (size_t)n0 * MROW);
    for (int i = threadIdx.x; i < 2 * MROW / 4; i += 256)
        reinterpret_cast<float4*>(sA)[i] = g[i];
    __syncthreads();

    int d  = threadIdx.x & (CC - 1);
    int nl = threadIdx.x >> 7;
    const float* a = sA + nl * MROW;

    float acc[9];
    #pragma unroll
    for (int m = 0; m < 9; ++m) acc[m] = 0.f;

    #pragma unroll 2
    for (int cc = 0; cc < CC; ++cc) {
        float w0 = W0[cc * CC + d];
        float w1 = W1[cc * CC + d];
        float w2 = W2[cc * CC + d];
        acc[0] = fmaf(a[cc],           w0, acc[0]);
        acc[1] = fmaf(a[CC + cc],      w1, acc[1]);
        acc[2] = fmaf(a[2 * CC + cc],  w1, acc[2]);
        acc[3] = fmaf(a[3 * CC + cc],  w1, acc[3]);
        acc[4] = fmaf(a[4 * CC + cc],  w2, acc[4]);
        acc[5] = fmaf(a[5 * CC + cc],  w2, acc[5]);
        acc[6] = fmaf(a[6 * CC + cc],  w2, acc[6]);
        acc[7] = fmaf(a[7 * CC + cc],  w2, acc[7]);
        acc[8] = fmaf(a[8 * CC + cc],  w2, acc[8]);
    }

    const float inv = 0.08838834764831845f;  // 1/sqrt(128)
    size_t ob = (size_t)(n0 + nl) * MROW;
    out[ob + d] = acc[0] * inv + b0[d];
    #pragma unroll
    for (int m = 0; m < 3; ++m) out[ob + CC + d * 3 + m]     = acc[1 + m] * inv;
    #pragma unroll
    for (int m = 0; m < 5; ++m) out[ob + 4 * CC + d * 5 + m] = acc[4 + m] * inv;
}

extern "C" void kernel_launch(void* const* d_in, const int* in_sizes, int n_in,
                              void* d_out, int out_size, void* d_ws, size_t ws_size,
                              hipStream_t stream)
{
    const float* node_feat  = (const float*)d_in[0];
    const float* edge_attr  = (const float*)d_in[1];
    const float* edge_rsh   = (const float*)d_in[2];
    const int*   edge_index = (const int*)  d_in[3];
    const float* Ws1 = (const float*)d_in[4];
    const float* bs1 = (const float*)d_in[5];
    const float* Ws2 = (const float*)d_in[6];
    const float* bs2 = (const float*)d_in[7];
    const float* Wr1 = (const float*)d_in[8];
    const float* br1 = (const float*)d_in[9];
    const float* Wr2 = (const float*)d_in[10];
    const float* br2 = (const float*)d_in[11];
    const float* W0  = (const float*)d_in[12];
    const float* b0  = (const float*)d_in[13];
    const float* W1  = (const float*)d_in[14];
    const float* W2  = (const float*)d_in[15];
    float* out = (float*)d_out;

    zero_deg_kernel<<<(NN + 255) / 256, 256, 0, stream>>>();
    hist_kernel<<<EE / 256, 256, 0, stream>>>(edge_index);
    scan_kernel<<<1, 256, 0, stream>>>();
    perm_kernel<<<EE / 256, 256, 0, stream>>>(edge_index);
    proj_kernel<<<(NN + 63) / 64, 64, 0, stream>>>(node_feat, Ws1, bs1);
    mlp_kernel<<<EE / 128, 128, 0, stream>>>(
        node_feat, edge_attr, edge_index, Ws2, bs2, Wr1, br1, Wr2, br2);
    gather_kernel<<<NN / 8, 512, 0, stream>>>(edge_rsh);
    lin2_kernel<<<NN / 2, 256, 0, stream>>>(W0, b0, W1, W2, out);
}